// Round 3
// baseline (226.132 us; speedup 1.0000x reference)
//
#include <hip/hip_runtime.h>

// GraphSAGE 2-layer + linear head, N=50000, E=600000, C=128 everywhere.
// R12: FUSE agg+gemm per layer. Evidence: all 6 kernels < 42us (none ever
//      beats the harness fills in top-5) yet sum=226 => aggs ~40us each are
//      dominant; all inter-kernel traffic is L2-cheap (R9->R11 arc: moving
//      +/-50MB moved +/-1.5us). Fused layout: 32 nodes/block, 4 waves;
//      mean -> 8KB swizzled LDS (mh tensor ELIMINATED); weights -> 16KB
//      quarter-stage x4 rounds (LDS total 32KB, launch_bounds(256,4) ->
//      4 blocks/CU, agg concurrency preserved); layer2 also does the head
//      (x1 A-frags reused in-reg, x2 via 8KB swizzled LDS, R11-proven).
//      Bonus: fused kernels (~45-60us) EXCEED the 42us fill floor =>
//      first-ever per-dispatch counters for the dominant phase next round.
// Ledger: R10 fusion+scan-fold NEUTRAL (+2.3, pred -20); R11 Wt3-staging -3
//      (pred -15) => L2 traffic is ~3us/100MB, not 15. fp8 NEUTRAL, ILP
//      NEUTRAL, XCD-slice NEGATIVE on agg => latency-bound, not byte-bound.

typedef _Float16 f16;
typedef unsigned int u32;
typedef __attribute__((ext_vector_type(4))) _Float16 f16x4;
typedef __attribute__((ext_vector_type(8))) _Float16 f16x8;
typedef __attribute__((ext_vector_type(4))) float f32x4;

#define RNB 128   // radix blocks (256 bins x 128 = 32768 hist entries)

// ---- prep: [0,cb) convert x -> f16 | [cb,cb+wb) weights | rest: radix hist
// weights k-chunked transposed, 3 tables contiguous (32768 f16 each):
// wt[w][(chunk*128 + n)*8 + j] = W_w[k=chunk*8+j][n], W = [WA;WB] stacked.
__global__ void prep_kernel(const float* __restrict__ x, f16* __restrict__ xh, int n4,
                            const int* __restrict__ ei, int* __restrict__ ghist, int E,
                            const float* __restrict__ W1l, const float* __restrict__ W1r,
                            const float* __restrict__ W2l, const float* __restrict__ W2r,
                            const float* __restrict__ Wlin, f16* __restrict__ wt,
                            int cb, int wb) {
  int b = blockIdx.x;
  if (b < cb) {
    int i = b * 256 + threadIdx.x;
    if (i < n4) {
      const float4 v = ((const float4*)x)[i];
      f16x4 h = { (f16)v.x, (f16)v.y, (f16)v.z, (f16)v.w };
      ((f16x4*)xh)[i] = h;
    }
  } else if (b < cb + wb) {
    int tid = (b - cb) * 256 + threadIdx.x;   // 0 .. 3*32768
    int w = tid >> 15, idx = tid & 32767;
    int j = idx & 7, n = (idx >> 3) & 127, chunk = idx >> 10;
    int k = chunk * 8 + j;
    float v;
    if (w == 0) v = (k < 128) ? W1l[k * 128 + n] : W1r[(k - 128) * 128 + n];
    else if (w == 1) v = (k < 128) ? W2l[k * 128 + n] : W2r[(k - 128) * 128 + n];
    else v = Wlin[k * 128 + n];
    wt[tid] = (f16)v;
  } else {
    __shared__ int h[256];
    int tid = threadIdx.x, rb = b - cb - wb;   // 0..RNB-1
    h[tid] = 0;
    __syncthreads();
    int per = (E + RNB - 1) / RNB;
    int s = rb * per, e = s + per; if (e > E) e = E;
    for (int i = s + tid; i < e; i += 256) atomicAdd(&h[ei[E + i] >> 8], 1);
    __syncthreads();
    ghist[tid * RNB + rb] = h[tid];
  }
}

// shfl-based exclusive scan over 256 threads (4 waves); one barrier.
__device__ inline int block_excl_scan256(int v, int* ws) {
  int lane = threadIdx.x & 63, w = threadIdx.x >> 6;
  int incl = v;
#pragma unroll
  for (int o = 1; o < 64; o <<= 1) {
    int u = __shfl_up(incl, o);
    if (lane >= o) incl += u;
  }
  if (lane == 63) ws[w] = incl;
  __syncthreads();
  int base = 0;
#pragma unroll
  for (int i = 0; i < 4; ++i) base += (i < w) ? ws[i] : 0;
  return base + incl - v;
}

// deterministic scatter into per-(block,bin) ranges; LDS cursors only.
__global__ void radix_scatter(const int* __restrict__ ei, const int* __restrict__ ghist,
                              u32* __restrict__ tmp, int E) {
  __shared__ int cur[256];
  __shared__ int ws[4];
  int tid = threadIdx.x, b = blockIdx.x;
  const int* row = ghist + tid * RNB;
  int part = 0, rest = 0;
  for (int i = 0; i < b; ++i) part += row[i];
  for (int i = b; i < RNB; ++i) rest += row[i];
  int total = part + rest;
  int excl = block_excl_scan256(total, ws);
  cur[tid] = excl + part;
  __syncthreads();
  int per = (E + RNB - 1) / RNB;
  int s = b * per, e = s + per; if (e > E) e = E;
  for (int i = s + tid; i < e; i += 256) {
    int d = ei[E + i], sr = ei[i];
    int pos = atomicAdd(&cur[d >> 8], 1);
    tmp[pos] = ((u32)sr << 8) | (u32)(d & 255);
  }
}

// one block per high-byte bucket: LDS low-byte hist + scan -> off[] + srcs.
__global__ void radix_bucket(const u32* __restrict__ tmp, const int* __restrict__ ghist,
                             int* __restrict__ srcs, int* __restrict__ off,
                             int N, int E, int HB) {
  __shared__ int h[256], sc[256], cur[256];
  __shared__ int bsc[257];
  __shared__ int ws[4];
  int tid = threadIdx.x, hb = blockIdx.x;
  const int* row = ghist + tid * RNB;
  int total = 0;
#pragma unroll 4
  for (int i = 0; i < RNB; ++i) total += row[i];
  int excl = block_excl_scan256(total, ws);
  bsc[tid] = excl;
  if (tid == 255) bsc[256] = E;
  h[tid] = 0;
  __syncthreads();
  int start = bsc[hb];
  int end = bsc[hb + 1];
  for (int i = start + tid; i < end; i += 256) atomicAdd(&h[tmp[i] & 255u], 1);
  __syncthreads();
  sc[tid] = h[tid];
  __syncthreads();
  for (int o = 1; o < 256; o <<= 1) {
    int u = (tid >= o) ? sc[tid - o] : 0;
    __syncthreads();
    sc[tid] += u;
    __syncthreads();
  }
  int exclb = sc[tid] - h[tid];
  int v = (hb << 8) + tid;
  if (v < N) off[v] = start + exclb;
  if (hb == 0 && tid == 0) off[N] = E;
  cur[tid] = start + exclb;
  __syncthreads();
  for (int i = start + tid; i < end; i += 256) {
    u32 p = tmp[i];
    int pos = atomicAdd(&cur[p & 255u], 1);
    srcs[pos] = (int)(p >> 8);
  }
}

// ---- FUSED per-layer kernel: block = 32 consecutive nodes, 4 waves.
// Phase A (agg, R3-proven inner body): 4 passes, wave handles node pair
//   (p*8 + wave*2); mean -> 8KB XOR-swizzled LDS tile.
// Phase B (gemm): out32x128 = act([mean|feat] @ WtA + bA); B streamed via
//   16KB LDS quarter-stages (4 rounds). HEAD additionally computes
//   out = [feat|x2] @ WtB + bB with x2 through a second 8KB swizzled tile
//   and feat A-frags reused in-register (R11-proven trick).
// LDS: [0,8192) f16 B-stage | [8192,12288) mean | [12288,16384) x2 = 32KB.
#define AGG_R 6
template <bool HEAD>
__global__ __launch_bounds__(256, 4) void fused_kernel(
    const f16* __restrict__ feat,   // gather source AND root operand (xh / x1h)
    const int* __restrict__ off, const int* __restrict__ srcs,
    const f16* __restrict__ WtA, const f16* __restrict__ WtB,
    const float* __restrict__ bA, const float* __restrict__ bB,
    void* __restrict__ outp, int n) {
  __shared__ f16 lds[16384];
  int tid = threadIdx.x;
  int wave = tid >> 6, lane = tid & 63;
  int sub = lane >> 4, n15 = lane & 15;
  int base = blockIdx.x * 32;

  // stage(0) of WtA early; covered by the post-agg barrier
#pragma unroll
  for (int i = 0; i < 4; ++i)
    ((f16x8*)lds)[i * 256 + tid] = ((const f16x8*)WtA)[i * 256 + tid];

  // ---- Phase A: aggregate 32 nodes (4 passes x 4 waves x 2 nodes)
#pragma unroll 1
  for (int p = 0; p < 4; ++p) {
    int ln0 = p * 8 + wave * 2;
    int w0 = base + ln0, w1 = w0 + 1;
    bool a0 = w0 < n, a1 = w1 < n;
    int beg0 = a0 ? off[w0] : 0;
    int end0 = a0 ? off[w0 + 1] : 0;
    int beg1 = end0;                       // CSR contiguity
    int end1 = a1 ? off[w1 + 1] : end0;
    int deg0 = end0 - beg0, deg1 = end1 - beg1;

    int s0[AGG_R], s1[AGG_R];
    bool v0[AGG_R], v1[AGG_R];
#pragma unroll
    for (int k = 0; k < AGG_R; ++k) {
      int pp = 4 * k + sub;
      v0[k] = pp < deg0;  s0[k] = v0[k] ? srcs[beg0 + pp] : 0;
      v1[k] = pp < deg1;  s1[k] = v1[k] ? srcs[beg1 + pp] : 0;
    }
    f16x8 g0[AGG_R], g1[AGG_R];
#pragma unroll
    for (int k = 0; k < AGG_R; ++k) {
      if (v0[k]) g0[k] = *(const f16x8*)(feat + (size_t)s0[k] * 128 + n15 * 8);
      if (v1[k]) g1[k] = *(const f16x8*)(feat + (size_t)s1[k] * 128 + n15 * 8);
    }
    float acc0[8] = {}, acc1[8] = {};
#pragma unroll
    for (int k = 0; k < AGG_R; ++k) {
      if (v0[k]) {
#pragma unroll
        for (int j = 0; j < 8; ++j) acc0[j] += (float)g0[k][j];
      }
      if (v1[k]) {
#pragma unroll
        for (int j = 0; j < 8; ++j) acc1[j] += (float)g1[k][j];
      }
    }
    for (int e = beg0 + 4 * AGG_R; e < end0; e += 4) {   // rare deg>24 tail
      if (sub < end0 - e) {
        int s = srcs[e + sub];
        f16x8 g = *(const f16x8*)(feat + (size_t)s * 128 + n15 * 8);
#pragma unroll
        for (int j = 0; j < 8; ++j) acc0[j] += (float)g[j];
      }
    }
    for (int e = beg1 + 4 * AGG_R; e < end1; e += 4) {
      if (sub < end1 - e) {
        int s = srcs[e + sub];
        f16x8 g = *(const f16x8*)(feat + (size_t)s * 128 + n15 * 8);
#pragma unroll
        for (int j = 0; j < 8; ++j) acc1[j] += (float)g[j];
      }
    }
#pragma unroll
    for (int j = 0; j < 8; ++j) {
      acc0[j] += __shfl_xor(acc0[j], 16);
      acc0[j] += __shfl_xor(acc0[j], 32);
      acc1[j] += __shfl_xor(acc1[j], 16);
      acc1[j] += __shfl_xor(acc1[j], 32);
    }
    if (sub == 0) {
      float inv = 1.0f / fmaxf((float)deg0, 1.0f);
      f16x8 o;
#pragma unroll
      for (int j = 0; j < 8; ++j) o[j] = (f16)(acc0[j] * inv);
      *(f16x8*)(lds + 8192 + ln0 * 128 + ((n15 ^ (ln0 & 15)) << 3)) = o;
    } else if (sub == 1) {
      float inv = 1.0f / fmaxf((float)deg1, 1.0f);
      int ln1 = ln0 + 1;
      f16x8 o;
#pragma unroll
      for (int j = 0; j < 8; ++j) o[j] = (f16)(acc1[j] * inv);
      *(f16x8*)(lds + 8192 + ln1 * 128 + ((n15 ^ (ln1 & 15)) << 3)) = o;
    }
  }
  __syncthreads();   // means + stage(0) visible

  // ---- Phase B: gemm. wave -> (rowgroup rg, colhalf ch); 16 rows x 64 cols.
  int rg = wave & 1, ch = wave >> 1;
  int rowl = rg * 16 + n15;
  int colb = ch * 64;

  f16x8 a[8];
#pragma unroll
  for (int kk = 0; kk < 4; ++kk)    // mean part (k 0..127) from swizzled LDS
    a[kk] = *(const f16x8*)(lds + 8192 + rowl * 128 + (((kk * 4 + sub) ^ n15) << 3));
  {
    int node = base + rowl; if (node >= n) node = n - 1;   // clamped tail load
    const f16* bp = feat + (size_t)node * 128 + sub * 8;
#pragma unroll
    for (int kk = 4; kk < 8; ++kk) a[kk] = *(const f16x8*)(bp + (kk - 4) * 32);
  }

  f32x4 acc[4] = {};
#pragma unroll
  for (int q = 0; q < 4; ++q) {
#pragma unroll
    for (int kk = 2 * q; kk < 2 * q + 2; ++kk)
#pragma unroll
      for (int t = 0; t < 4; ++t) {
        f16x8 bfr = ((const f16x8*)lds)[((kk * 4 + sub) & 7) * 128 + colb + t * 16 + n15];
        acc[t] = __builtin_amdgcn_mfma_f32_16x16x32_f16(a[kk], bfr, acc[t], 0, 0, 0);
      }
    if (q < 3) {
      __syncthreads();
#pragma unroll
      for (int i = 0; i < 4; ++i)
        ((f16x8*)lds)[i * 256 + tid] = ((const f16x8*)WtA)[(q + 1) * 1024 + i * 256 + tid];
      __syncthreads();
    }
  }

  if (!HEAD) {
    // epilogue: x1 = relu(acc + bA) -> f16 out
#pragma unroll
    for (int t = 0; t < 4; ++t) {
      float bv = bA[colb + t * 16 + n15];
#pragma unroll
      for (int i = 0; i < 4; ++i) {
        int row = base + rg * 16 + sub * 4 + i;
        if (row < n) {
          float v = fmaxf(acc[t][i] + bv, 0.f);
          ((f16*)outp)[(size_t)row * 128 + colb + t * 16 + n15] = (f16)v;
        }
      }
    }
  } else {
    __syncthreads();   // all waves done with last WtA stage region
    // x2 = relu(acc + bA) -> swizzled LDS tile; stage WtB round 0
#pragma unroll
    for (int t = 0; t < 4; ++t) {
      float bv = bA[colb + t * 16 + n15];
      int col = colb + t * 16 + n15;
      int cchunk = col >> 3, coff = col & 7;
#pragma unroll
      for (int i = 0; i < 4; ++i) {
        int rw = rg * 16 + sub * 4 + i;
        float v = fmaxf(acc[t][i] + bv, 0.f);
        lds[12288 + rw * 128 + (((cchunk ^ (rw & 15)) << 3) | coff)] = (f16)v;
      }
    }
#pragma unroll
    for (int i = 0; i < 4; ++i)
      ((f16x8*)lds)[i * 256 + tid] = ((const f16x8*)WtB)[i * 256 + tid];
    __syncthreads();

    f16x8 a2[4];
#pragma unroll
    for (int kk2 = 0; kk2 < 4; ++kk2)
      a2[kk2] = *(const f16x8*)(lds + 12288 + rowl * 128 + (((kk2 * 4 + sub) ^ n15) << 3));

    f32x4 acc3[4] = {};
#pragma unroll
    for (int q = 0; q < 4; ++q) {
#pragma unroll
      for (int kk = 2 * q; kk < 2 * q + 2; ++kk)
#pragma unroll
        for (int t = 0; t < 4; ++t) {
          f16x8 bfr = ((const f16x8*)lds)[((kk * 4 + sub) & 7) * 128 + colb + t * 16 + n15];
          f16x8 av = (kk < 4) ? a[4 + kk] : a2[kk - 4];   // [x1 | x2]
          acc3[t] = __builtin_amdgcn_mfma_f32_16x16x32_f16(av, bfr, acc3[t], 0, 0, 0);
        }
      if (q < 3) {
        __syncthreads();
#pragma unroll
        for (int i = 0; i < 4; ++i)
          ((f16x8*)lds)[i * 256 + tid] = ((const f16x8*)WtB)[(q + 1) * 1024 + i * 256 + tid];
        __syncthreads();
      }
    }
#pragma unroll
    for (int t = 0; t < 4; ++t) {
      float bv = bB[colb + t * 16 + n15];
#pragma unroll
      for (int i = 0; i < 4; ++i) {
        int row = base + rg * 16 + sub * 4 + i;
        if (row < n)
          ((float*)outp)[(size_t)row * 128 + colb + t * 16 + n15] = acc3[t][i] + bv;
      }
    }
  }
}

extern "C" void kernel_launch(void* const* d_in, const int* in_sizes, int n_in,
                              void* d_out, int out_size, void* d_ws, size_t ws_size,
                              hipStream_t stream) {
  (void)n_in; (void)out_size; (void)ws_size;
  const float* x    = (const float*)d_in[0];
  const int*   ei   = (const int*)d_in[1];
  const float* W1l  = (const float*)d_in[2];
  const float* b1l  = (const float*)d_in[3];
  const float* W1r  = (const float*)d_in[4];
  const float* W2l  = (const float*)d_in[5];
  const float* b2l  = (const float*)d_in[6];
  const float* W2r  = (const float*)d_in[7];
  const float* Wlin = (const float*)d_in[8];
  const float* blin = (const float*)d_in[9];
  const int N = in_sizes[0] / 128;
  const int E = in_sizes[1] / 2;

  char* ws = (char*)d_ws;
  size_t o = 0;
  auto alloc = [&](size_t bytes) {
    char* p = ws + o;
    o = (o + bytes + 255) & ~(size_t)255;
    return p;
  };
  f16*  xh   = (f16*)alloc((size_t)N * 128 * 2);
  f16*  x1h  = (f16*)alloc((size_t)N * 128 * 2);
  f16*  wt   = (f16*)alloc((size_t)3 * 32768 * 2);   // wt1|wt2|wt3 contiguous
  int*  off  = (int*)alloc(((size_t)N + 1) * 4);
  int*  srcs = (int*)alloc((size_t)E * 4);
  u32*  tmp  = (u32*)alloc((size_t)E * 4);           // packed (src<<8)|dstLow
  int*  ghist= (int*)alloc(256 * RNB * 4);
  f16* wt1 = wt, *wt2 = wt + 32768, *wt3 = wt + 65536;

  const int n4 = N * 128 / 4;
  const int cb = (n4 + 255) / 256;           // convert blocks
  const int wb = (3 * 32768) / 256;          // weight blocks (384)
  const int HB = (N + 255) / 256;            // high-byte buckets (196)

  // prep (convert + weights + radix hist)
  prep_kernel<<<cb + wb + RNB, 256, 0, stream>>>(x, xh, n4, ei, ghist, E,
                                                 W1l, W1r, W2l, W2r, Wlin, wt, cb, wb);
  // CSR build (atomic-free; global prefix rebuilt inline)
  radix_scatter<<<RNB, 256, 0, stream>>>(ei, ghist, tmp, E);
  radix_bucket<<<HB, 256, 0, stream>>>(tmp, ghist, srcs, off, N, E, HB);

  const int fusedBlocks = (N + 31) / 32;     // 1563

  // layer 1 fused: x1 = relu(mean(x) @ W1_l + x @ W1_r + b1)
  fused_kernel<false><<<fusedBlocks, 256, 0, stream>>>(
      xh, off, srcs, wt1, (const f16*)nullptr, b1l, (const float*)nullptr, x1h, N);
  // layer 2 + head fused: x2 = relu(mean(x1) @ W2 + b2); out = [x1|x2] @ W3 + b3
  fused_kernel<true><<<fusedBlocks, 256, 0, stream>>>(
      x1h, off, srcs, wt2, wt3, b2l, blin, d_out, N);
}